// Round 5
// baseline (212.908 us; speedup 1.0000x reference)
//
#include <hip/hip_runtime.h>
#include <math.h>

#define SEQ 2048
#define NBATCH 2
#define DEMB 1024
#define NH 16
#define HD 64
#define NROWS (NBATCH * SEQ) // 4096

typedef __attribute__((ext_vector_type(8))) short short8;   // 8 bf16 (4 VGPR)
typedef __attribute__((ext_vector_type(4))) float f32x4;    // MFMA acc

__device__ __forceinline__ unsigned short f2bf(float f) {
    unsigned int u = __float_as_uint(f);
    u = (u + 0x7FFFu + ((u >> 16) & 1u)) >> 16;   // RNE
    return (unsigned short)u;
}
__device__ __forceinline__ unsigned short f2bf_fast(float f) {
    return (unsigned short)((__float_as_uint(f) + 0x8000u) >> 16); // round-half-up
}

// Direct global->LDS DMA, 16B per lane. LDS dest = wave-uniform base + lane*16.
__device__ __forceinline__ void gload_lds16(const void* g, void* l) {
    typedef const __attribute__((address_space(1))) unsigned int* gp_t;
    typedef __attribute__((address_space(3))) unsigned int* lp_t;
    __builtin_amdgcn_global_load_lds((gp_t)g, (lp_t)l, 16, 0, 0);
}

// ============================================================================
// Cast fp32 inputs to bf16. Wq pre-scaled by 0.125*log2(e) (exp2-domain
// softmax downstream).
// ============================================================================
__global__ __launch_bounds__(256) void cast_bf16(
    const float* __restrict__ x, const float* __restrict__ wq,
    const float* __restrict__ wk, const float* __restrict__ wv,
    const float* __restrict__ wo,
    unsigned short* __restrict__ Xb, unsigned short* __restrict__ Wb,
    unsigned short* __restrict__ Wob)
{
    const int q = blockIdx.x * 256 + threadIdx.x; // quad index
    float4 v; unsigned short* dst; float sc = 1.f;
    if (q < 1048576) {                       // X: 4194304 elems
        v = ((const float4*)x)[q];
        dst = Xb + q * 4;
    } else if (q < 1835008) {                // Wq|Wk|Wv concat: 3145728 elems
        const int e = (q - 1048576) * 4;
        const int which = e >> 20;
        const int off = e & 1048575;
        const float* s = (which == 0) ? wq : (which == 1) ? wk : wv;
        v = *(const float4*)&s[off];
        sc = (which == 0) ? 0.18033688011112042f : 1.f;  // 0.125*log2(e)
        dst = Wb + e;
    } else {                                 // Wo: 1048576 elems
        const int j = q - 1835008;
        v = ((const float4*)wo)[j];
        dst = Wob + j * 4;
    }
    ushort4 o;
    o.x = f2bf(v.x * sc); o.y = f2bf(v.y * sc);
    o.z = f2bf(v.z * sc); o.w = f2bf(v.w * sc);
    *(ushort4*)dst = o;
}

// ============================================================================
// bf16 MFMA NT-GEMM, m97 staging: global_load_lds width-16 into linear LDS,
// with PRE-SWIZZLED global source so LDS content matches the swizzled layout
// LDS[r][slot] = global[r][slot ^ ((r>>1)&3)] (2-way-free fragment reads).
// 128x128 tile, BK=32, 4 waves. Q,K,V written bf16 [b,h,s,d].
// ============================================================================
__global__ __launch_bounds__(256) void gemm_qkv(
    const unsigned short* __restrict__ Xb, const unsigned short* __restrict__ Wb,
    unsigned short* __restrict__ Qb, unsigned short* __restrict__ Kb,
    unsigned short* __restrict__ Vb)
{
    __shared__ __align__(16) short As[128 * 32];
    __shared__ __align__(16) short Bs[128 * 32];

    const int tid = threadIdx.x;
    const int m0 = blockIdx.y * 128, n0 = blockIdx.x * 128;
    const int lane = tid & 63, w = tid >> 6;
    const int wr = w >> 1, wc = w & 1;
    const int fr = lane & 15, fq = lane >> 4;

    // staging geometry: wave w, instr i covers chunks (w*2+i)*64 + lane
    int soff[2];   // element offset (row*1024 + cg*8) into source matrix
#pragma unroll
    for (int i = 0; i < 2; ++i) {
        const int chunk = (w * 2 + i) * 64 + lane;
        const int row = chunk >> 2;
        const int cg = (chunk & 3) ^ ((row >> 1) & 3);  // pre-swizzled source
        soff[i] = row * 1024 + cg * 8;
    }

    int offA[4], offB[4];
#pragma unroll
    for (int m = 0; m < 4; ++m) {
        const int rA = wr * 64 + m * 16 + fr;
        offA[m] = rA * 32 + ((fq ^ ((rA >> 1) & 3)) * 8);
        const int rB = wc * 64 + m * 16 + fr;
        offB[m] = rB * 32 + ((fq ^ ((rB >> 1) & 3)) * 8);
    }

    f32x4 acc[4][4];
#pragma unroll
    for (int m = 0; m < 4; ++m)
#pragma unroll
        for (int n = 0; n < 4; ++n) acc[m][n] = (f32x4){0.f, 0.f, 0.f, 0.f};

    const unsigned short* Abase = Xb + (size_t)m0 * 1024;
    const unsigned short* Bbase = Wb + (size_t)n0 * 1024;

    for (int k0 = 0; k0 < 1024; k0 += 32) {
        __syncthreads();   // LDS free (prev compute done)
#pragma unroll
        for (int i = 0; i < 2; ++i) {
            gload_lds16(Abase + soff[i] + k0, As + (w * 2 + i) * 512);
            gload_lds16(Bbase + soff[i] + k0, Bs + (w * 2 + i) * 512);
        }
        __syncthreads();   // vmcnt(0) drain: tile ready
        short8 af[4], bg[4];
#pragma unroll
        for (int m = 0; m < 4; ++m) af[m] = *(const short8*)&As[offA[m]];
#pragma unroll
        for (int n = 0; n < 4; ++n) bg[n] = *(const short8*)&Bs[offB[n]];
        __builtin_amdgcn_s_setprio(1);
#pragma unroll
        for (int m = 0; m < 4; ++m)
#pragma unroll
            for (int n = 0; n < 4; ++n)
                acc[m][n] = __builtin_amdgcn_mfma_f32_16x16x32_bf16(
                    af[m], bg[n], acc[m][n], 0, 0, 0);
        __builtin_amdgcn_s_setprio(0);
    }

#pragma unroll
    for (int n = 0; n < 4; ++n) {
        const int col = n0 + wc * 64 + n * 16 + fr;
        const int which = col >> 10;
        const int h = (col >> 6) & 15;
        const int d = col & 63;
        unsigned short* Out = (which == 0) ? Qb : (which == 1) ? Kb : Vb;
#pragma unroll
        for (int m = 0; m < 4; ++m) {
            const int rowb = m0 + wr * 64 + m * 16 + fq * 4;
#pragma unroll
            for (int r = 0; r < 4; ++r) {
                const int row = rowb + r;
                const int b = row >> 11, s = row & 2047;
                Out[(((size_t)b * NH + h) * SEQ + s) * HD + d] =
                    f2bf(acc[m][n][r]);
            }
        }
    }
}

// ============================================================================
// V [b,h,s,d] -> Vt [b,h,d,s] via LDS tile.
// ============================================================================
__global__ __launch_bounds__(256) void transpose_v(
    const unsigned short* __restrict__ Vb, unsigned short* __restrict__ Vtb)
{
    __shared__ short T[64][72];
    const int s0tile = blockIdx.x * 64;
    const size_t bh = blockIdx.y;
    const unsigned short* src = Vb + bh * SEQ * HD;
    unsigned short* dst = Vtb + bh * (size_t)HD * SEQ;
    const int t = threadIdx.x;
    const int sr = t >> 3, sc = t & 7;

    const short8 a = *(const short8*)&src[(size_t)(s0tile + sr) * HD + sc * 8];
    const short8 bb = *(const short8*)&src[(size_t)(s0tile + sr + 32) * HD + sc * 8];
    *(short8*)&T[sr][sc * 8] = a;
    *(short8*)&T[sr + 32][sc * 8] = bb;
    __syncthreads();

    const int d = t >> 2, s0 = (t & 3) * 16;
    short8 o0, o1;
#pragma unroll
    for (int i = 0; i < 8; ++i) {
        o0[i] = T[s0 + i][d];
        o1[i] = T[s0 + 8 + i][d];
    }
    *(short8*)&dst[(size_t)d * SEQ + s0tile + s0] = o0;
    *(short8*)&dst[(size_t)d * SEQ + s0tile + s0 + 8] = o1;
}

// ============================================================================
// MFMA flash attention v3: NO barriers, NO K/V LDS staging.
// K/Vt fragments load directly from global (L1/L2-resident tiles; rows are
// exactly the MFMA fragment layout). 8 waves/block, wave-paired (w<4: qt=bx,
// w>=4: qt=15-bx -> 34 tiles per SIMD, balanced). Waves fully independent.
// P roundtrip via wave-private swizzled LDS, packed ds_write_b64.
// ============================================================================
__global__ __launch_bounds__(512, 2) void flash_mfma3(
    const unsigned short* __restrict__ Qb, const unsigned short* __restrict__ Kb,
    const unsigned short* __restrict__ Vtb, unsigned short* __restrict__ ctx)
{
    __shared__ __align__(16) short Ps[8 * 2048];  // per-wave P [32 q][64 kv]

    const int bx = blockIdx.x;   // 0..7
    const int h  = blockIdx.y;
    const int b  = blockIdx.z;
    const size_t bh = (size_t)b * NH + h;
    const unsigned short* __restrict__ Qg = Qb  + bh * SEQ * HD;
    const unsigned short* __restrict__ Kg = Kb  + bh * SEQ * HD;
    const unsigned short* __restrict__ Vg = Vtb + bh * (size_t)HD * SEQ;

    const int tid = threadIdx.x;
    const int lane = tid & 63, w = tid >> 6;
    const int fr = lane & 15, fq = lane >> 4;

    const int qt = (w < 4) ? bx : 15 - bx;
    const int qbase = qt * 128 + (w & 3) * 32;
    const int jmaxw = (qbase + 31) >> 6;   // last kv tile this wave touches

    // Q fragments (MFMA B-operand of the swapped QK^T)
    short8 qa[2][2];
#pragma unroll
    for (int m = 0; m < 2; ++m)
#pragma unroll
        for (int ks = 0; ks < 2; ++ks)
            qa[m][ks] = *(const short8*)&Qg[(size_t)(qbase + m * 16 + fr) * HD + ks * 32 + fq * 8];

    f32x4 o[2][4];
    float mold[2], lsum[2];
#pragma unroll
    for (int m = 0; m < 2; ++m) {
        mold[m] = -3e38f; lsum[m] = 0.f;
#pragma unroll
        for (int n = 0; n < 4; ++n) o[m][n] = (f32x4){0.f, 0.f, 0.f, 0.f};
    }

    short* const Pw = Ps + w * 2048;
    const int swz = (fr & 7) << 3;

    for (int j = 0; j <= jmaxw; ++j) {
        const int kvb = j * 64;

        // ---- direct global fragment loads (K first, V used ~600cyc later) ----
        short8 kf[2][4], vf[2][4];
#pragma unroll
        for (int ks = 0; ks < 2; ++ks)
#pragma unroll
            for (int n = 0; n < 4; ++n)
                kf[ks][n] = *(const short8*)&Kg[(size_t)(kvb + n * 16 + fr) * HD + ks * 32 + fq * 8];
#pragma unroll
        for (int ks = 0; ks < 2; ++ks)
#pragma unroll
            for (int n = 0; n < 4; ++n)
                vf[ks][n] = *(const short8*)&Vg[(size_t)(n * 16 + fr) * SEQ + kvb + ks * 32 + fq * 8];

        // ---- S^T = K Q^T : lane holds q-col = m*16+fr ----
        f32x4 st[4][2];
#pragma unroll
        for (int n = 0; n < 4; ++n)
#pragma unroll
            for (int m = 0; m < 2; ++m) st[n][m] = (f32x4){0.f, 0.f, 0.f, 0.f};
#pragma unroll
        for (int ks = 0; ks < 2; ++ks) {
            __builtin_amdgcn_s_setprio(1);
#pragma unroll
            for (int n = 0; n < 4; ++n)
#pragma unroll
                for (int m = 0; m < 2; ++m)
                    st[n][m] = __builtin_amdgcn_mfma_f32_16x16x32_bf16(
                        kf[ks][n], qa[m][ks], st[n][m], 0, 0, 0);
            __builtin_amdgcn_s_setprio(0);
        }

        // ---- causal mask (kv = kvb+n*16+fq*4+r, q = qbase+m*16+fr) ----
        if (kvb + 63 > qbase) {
#pragma unroll
            for (int n = 0; n < 4; ++n) {
                const int kv = kvb + n * 16 + fq * 4;
#pragma unroll
                for (int m = 0; m < 2; ++m) {
                    const int q = qbase + m * 16 + fr;
#pragma unroll
                    for (int r = 0; r < 4; ++r)
                        if (kv + r > q) st[n][m][r] = -3e38f;
                }
            }
        }

        // ---- row max (in-lane + 2 shfl across fq partners) ----
        float pmax[2];
#pragma unroll
        for (int m = 0; m < 2; ++m) {
            float t0 = fmaxf(fmaxf(st[0][m][0], st[0][m][1]), fmaxf(st[0][m][2], st[0][m][3]));
            float t1 = fmaxf(fmaxf(st[1][m][0], st[1][m][1]), fmaxf(st[1][m][2], st[1][m][3]));
            float t2 = fmaxf(fmaxf(st[2][m][0], st[2][m][1]), fmaxf(st[2][m][2], st[2][m][3]));
            float t3 = fmaxf(fmaxf(st[3][m][0], st[3][m][1]), fmaxf(st[3][m][2], st[3][m][3]));
            float t = fmaxf(fmaxf(t0, t1), fmaxf(t2, t3));
            t = fmaxf(t, __shfl_xor(t, 16));
            t = fmaxf(t, __shfl_xor(t, 32));
            pmax[m] = t;
        }

        // ---- defer-max (T13): rescale only if max grew > 8 (log2 units) ----
        const float growth = fmaxf(pmax[0] - mold[0], pmax[1] - mold[1]);
        if (!__all(growth <= 8.0f)) {
            float resc[2];
#pragma unroll
            for (int m = 0; m < 2; ++m) {
                const float nm = fmaxf(mold[m], pmax[m]);
                resc[m] = exp2f(mold[m] - nm);
                mold[m] = nm;
                lsum[m] *= resc[m];
            }
#pragma unroll
            for (int m = 0; m < 2; ++m)
#pragma unroll
                for (int rr = 0; rr < 4; ++rr) {
                    const float rsc = __shfl(resc[m], fq * 4 + rr);
#pragma unroll
                    for (int n = 0; n < 4; ++n) o[m][n][rr] *= rsc;
                }
        }

        // ---- exp2, row-sum, packed P -> wave-private LDS ----
#pragma unroll
        for (int m = 0; m < 2; ++m) {
            float rs = 0.f;
            const int prow = m * 16 + fr;
#pragma unroll
            for (int n = 0; n < 4; ++n) {
                const float p0 = exp2f(st[n][m][0] - mold[m]);
                const float p1 = exp2f(st[n][m][1] - mold[m]);
                const float p2 = exp2f(st[n][m][2] - mold[m]);
                const float p3 = exp2f(st[n][m][3] - mold[m]);
                rs += (p0 + p1) + (p2 + p3);
                ushort4 pk;
                pk.x = f2bf_fast(p0); pk.y = f2bf_fast(p1);
                pk.z = f2bf_fast(p2); pk.w = f2bf_fast(p3);
                *(ushort4*)&Pw[prow * 64 + ((n * 16 + fq * 4) ^ swz)] = pk;
            }
            rs += __shfl_xor(rs, 16);
            rs += __shfl_xor(rs, 32);
            lsum[m] += rs;
        }

        // ---- O += P @ Vt (same-wave DS write->read, compiler waits lgkm) ----
#pragma unroll
        for (int ks = 0; ks < 2; ++ks) {
            short8 pa[2];
#pragma unroll
            for (int m = 0; m < 2; ++m) {
                const int row = m * 16 + fr;
                pa[m] = *(const short8*)&Pw[row * 64 + ((ks * 32 + fq * 8) ^ swz)];
            }
            __builtin_amdgcn_s_setprio(1);
#pragma unroll
            for (int m = 0; m < 2; ++m)
#pragma unroll
                for (int n = 0; n < 4; ++n)
                    o[m][n] = __builtin_amdgcn_mfma_f32_16x16x32_bf16(
                        pa[m], vf[ks][n], o[m][n], 0, 0, 0);
            __builtin_amdgcn_s_setprio(0);
        }
    }

    // ---- epilogue: normalize (l redistributed), write ctx [b,s,h*64+d] ----
#pragma unroll
    for (int m = 0; m < 2; ++m)
#pragma unroll
        for (int rr = 0; rr < 4; ++rr) {
            const float lv = __shfl(lsum[m], fq * 4 + rr);
            const float inv = 1.f / lv;
            const int q = qbase + m * 16 + fq * 4 + rr;
            const size_t rowoff = ((size_t)b * SEQ + q) * DEMB + h * HD;
#pragma unroll
            for (int n = 0; n < 4; ++n)
                ctx[rowoff + n * 16 + fr] = f2bf(o[m][n][rr] * inv);
        }
}

// ============================================================================
// O-projection: ctx_bf16[4096][1024] @ Wob^T + bo -> out fp32, m97 staging.
// ============================================================================
__global__ __launch_bounds__(256) void gemm_out(
    const unsigned short* __restrict__ Cb, const unsigned short* __restrict__ Wob,
    const float* __restrict__ bo, float* __restrict__ Out)
{
    __shared__ __align__(16) short As[128 * 32];
    __shared__ __align__(16) short Bs[128 * 32];

    const int tid = threadIdx.x;
    const int m0 = blockIdx.y * 128, n0 = blockIdx.x * 128;
    const int lane = tid & 63, w = tid >> 6;
    const int wr = w >> 1, wc = w & 1;
    const int fr = lane & 15, fq = lane >> 4;

    int soff[2];
#pragma unroll
    for (int i = 0; i < 2; ++i) {
        const int chunk = (w * 2 + i) * 64 + lane;
        const int row = chunk >> 2;
        const int cg = (chunk & 3) ^ ((row >> 1) & 3);
        soff[i] = row * 1024 + cg * 8;
    }

    int offA[4], offB[4];
#pragma unroll
    for (int m = 0; m < 4; ++m) {
        const int rA = wr * 64 + m * 16 + fr;
        offA[m] = rA * 32 + ((fq ^ ((rA >> 1) & 3)) * 8);
        const int rB = wc * 64 + m * 16 + fr;
        offB[m] = rB * 32 + ((fq ^ ((rB >> 1) & 3)) * 8);
    }

    f32x4 acc[4][4];
#pragma unroll
    for (int m = 0; m < 4; ++m)
#pragma unroll
        for (int n = 0; n < 4; ++n) acc[m][n] = (f32x4){0.f, 0.f, 0.f, 0.f};

    const unsigned short* Abase = Cb + (size_t)m0 * 1024;
    const unsigned short* Bbase = Wob + (size_t)n0 * 1024;

    for (int k0 = 0; k0 < 1024; k0 += 32) {
        __syncthreads();
#pragma unroll
        for (int i = 0; i < 2; ++i) {
            gload_lds16(Abase + soff[i] + k0, As + (w * 2 + i) * 512);
            gload_lds16(Bbase + soff[i] + k0, Bs + (w * 2 + i) * 512);
        }
        __syncthreads();
        short8 af[4], bg[4];
#pragma unroll
        for (int m = 0; m < 4; ++m) af[m] = *(const short8*)&As[offA[m]];
#pragma unroll
        for (int n = 0; n < 4; ++n) bg[n] = *(const short8*)&Bs[offB[n]];
        __builtin_amdgcn_s_setprio(1);
#pragma unroll
        for (int m = 0; m < 4; ++m)
#pragma unroll
            for (int n = 0; n < 4; ++n)
                acc[m][n] = __builtin_amdgcn_mfma_f32_16x16x32_bf16(
                    af[m], bg[n], acc[m][n], 0, 0, 0);
        __builtin_amdgcn_s_setprio(0);
    }

#pragma unroll
    for (int n = 0; n < 4; ++n) {
        const int col = n0 + wc * 64 + n * 16 + fr;
        const float bias = bo[col];
#pragma unroll
        for (int m = 0; m < 4; ++m) {
            const int rowb = m0 + wr * 64 + m * 16 + fq * 4;
#pragma unroll
            for (int r = 0; r < 4; ++r)
                Out[(size_t)(rowb + r) * DEMB + col] = acc[m][n][r] + bias;
        }
    }
}

extern "C" void kernel_launch(void* const* d_in, const int* in_sizes, int n_in,
                              void* d_out, int out_size, void* d_ws, size_t ws_size,
                              hipStream_t stream) {
    const float* x  = (const float*)d_in[0];
    const float* Wq = (const float*)d_in[1];
    const float* Wk = (const float*)d_in[2];
    const float* Wv = (const float*)d_in[3];
    const float* Wo = (const float*)d_in[4];
    const float* bo = (const float*)d_in[5];
    float* out = (float*)d_out;

    char* w = (char*)d_ws;
    const size_t MB = 1024 * 1024;
    unsigned short* Qb   = (unsigned short*)(w);            //  8 MB
    unsigned short* Kb   = (unsigned short*)(w + 8  * MB);  //  8 MB
    unsigned short* Vb   = (unsigned short*)(w + 16 * MB);  //  8 MB [b,h,s,d]
    unsigned short* Cb   = (unsigned short*)(w + 24 * MB);  //  8 MB ctx
    unsigned short* Xb   = (unsigned short*)(w + 32 * MB);  //  8 MB (dead after gemm_qkv)
    unsigned short* Wb   = (unsigned short*)(w + 40 * MB);  //  6 MB (q|k|v)
    unsigned short* Wob  = (unsigned short*)(w + 46 * MB);  //  2 MB
    unsigned short* Vtb  = Xb;                              //  reuse: [b,h,d,s]

    cast_bf16<<<8192, 256, 0, stream>>>(x, Wq, Wk, Wv, Wo, Xb, Wb, Wob);
    gemm_qkv<<<dim3(24, 32), 256, 0, stream>>>(Xb, Wb, Qb, Kb, Vb);
    transpose_v<<<dim3(SEQ / 64, NBATCH * NH), 256, 0, stream>>>(Vb, Vtb);
    flash_mfma3<<<dim3(8, NH, NBATCH), 512, 0, stream>>>(Qb, Kb, Vtb, Cb);
    gemm_out<<<dim3(8, 32), 256, 0, stream>>>(Cb, Wob, bo, out);
}